// Round 8
// baseline (318.832 us; speedup 1.0000x reference)
//
#include <hip/hip_runtime.h>
#include <hip/hip_bf16.h>
#include <stdint.h>

typedef __attribute__((ext_vector_type(8))) short short8;   // 8 bf16 = 4 VGPRs
typedef __attribute__((ext_vector_type(4))) float f32x4;    // MFMA C/D frag

typedef __attribute__((address_space(3))) uint8_t lds_u8;
typedef __attribute__((address_space(1))) uint8_t glb_u8;

__device__ __forceinline__ void load_lds_16(const void* g, void* l) {
    __builtin_amdgcn_global_load_lds((glb_u8*)g, (lds_u8*)l, 16, 0, 0);
}

__device__ __forceinline__ unsigned short f2b(float f) {
    __hip_bfloat16 h = __float2bfloat16(f);
    return __builtin_bit_cast(unsigned short, h);
}
__device__ __forceinline__ ushort2 f2b2(float a, float b) {
    __hip_bfloat162 h = __float22bfloat162_rn(float2{a, b});
    ushort2 r;
    __builtin_memcpy(&r, &h, sizeof(r));
    return r;
}
__device__ __forceinline__ float b2f(unsigned short u) {
    unsigned int x = ((unsigned int)u) << 16;
    return __builtin_bit_cast(float, x);
}

constexpr int Bz = 32, Ss = 577, Dd = 768, Hh = 12;
constexpr int Mm = Bz * Ss;          // 18464
constexpr int QKV_N = 3 * Dd;        // 2304
constexpr float SCALE_L2E = 0.125f * 1.4426950408889634f;

// ---------------- fused prep: cast x->bf16 + both weight transposes ----------------
__global__ void prep_fused(const float* __restrict__ x, unsigned short* __restrict__ xb,
                           const float* __restrict__ w_qkv, unsigned short* __restrict__ wqkvT,
                           const float* __restrict__ w_fc, unsigned short* __restrict__ wfcT) {
    constexpr int N4 = Mm * Dd / 4;
    constexpr int NC = N4 / 256;
    constexpr int NT1 = (QKV_N / 32) * (Dd / 32);
    __shared__ unsigned short tile[32][33];

    const int bid = blockIdx.x;
    const int tid = threadIdx.x;
    if (bid < NC) {
        int i = bid * 256 + tid;
        float4 v = ((const float4*)x)[i];
        ushort4 o;
        o.x = f2b(v.x); o.y = f2b(v.y); o.z = f2b(v.z); o.w = f2b(v.w);
        ((ushort4*)xb)[i] = o;
        return;
    }
    const float* src; unsigned short* dst; int R, C, bx, by;
    if (bid < NC + NT1) {
        int b2 = bid - NC;
        src = w_qkv; dst = wqkvT; R = Dd; C = QKV_N;
        bx = b2 % (QKV_N / 32); by = b2 / (QKV_N / 32);
    } else {
        int b2 = bid - NC - NT1;
        src = w_fc; dst = wfcT; R = Dd; C = Dd;
        bx = b2 % (Dd / 32); by = b2 / (Dd / 32);
    }
    int c0 = bx * 32, r0 = by * 32;
    int tx = tid & 31, ty = tid >> 5;
#pragma unroll
    for (int i = 0; i < 4; ++i)
        tile[ty + i * 8][tx] = f2b(src[(size_t)(r0 + ty + i * 8) * C + c0 + tx]);
    __syncthreads();
#pragma unroll
    for (int i = 0; i < 4; ++i) {
        int rr = ty + i * 8;
        dst[(size_t)(c0 + rr) * R + r0 + tx] = tile[tx][rr];
    }
}

// ========= 256x256 TN GEMM, BK=32, triple-buffered counted-vmcnt (r6, 82us) =========
// Structural operating point under 1-block/CU lockstep (acc = 128 regs; r3 lesson).
template <int N_, bool OUT_BF16>
__global__ __launch_bounds__(512, 2)
void gemm256(const unsigned short* __restrict__ A,
             const unsigned short* __restrict__ Bt,
             const float* __restrict__ bias,
             void* __restrict__ Cout) {
    constexpr int K = 768;
    constexpr int NX = N_ / 256;
    constexpr int NY = (Mm + 255) / 256; // 73
    constexpr int NWG = NX * NY;
    constexpr int QC = NWG >> 3, RC = NWG & 7;
    extern __shared__ __align__(16) uint8_t smem[];   // 98304 B

    const int tid = threadIdx.x;
    const int wave = tid >> 6, lane = tid & 63;
    const int quad = lane >> 4, lc = lane & 15;
    const int wm = wave >> 2, wn = wave & 3;

    const int orig = blockIdx.y * NX + blockIdx.x;
    const int xcd = orig & 7, lid = orig >> 3;
    const int wgid = (xcd < RC ? xcd * (QC + 1) : RC * (QC + 1) + (xcd - RC) * QC) + lid;
    const int tm = (wgid / NX) * 256;
    const int tn = (wgid % NX) * 256;

    const int lrw = wave * 8 + (lane >> 3);
    const unsigned short* apS[2];
    const unsigned short* bpS[2];
#pragma unroll
    for (int s = 0; s < 2; ++s) {
        const int lr = s * 64 + lrw;
        const int chun = (lane & 7) ^ (lr & 7);
        const int trow = lr * 2 + (chun >> 2);
        int ar = tm + trow; if (ar >= Mm) ar = Mm - 1;
        apS[s] = A + (size_t)ar * K + (chun & 3) * 8;
        const int br = tn + trow;
        bpS[s] = Bt + (size_t)br * K + (chun & 3) * 8;
    }

    auto stage = [&](int kb, int buf) {
        uint8_t* d = smem + buf * 32768 + wave * 1024;
        const int ko = kb * 32;
        load_lds_16(apS[0] + ko, d);
        load_lds_16(apS[1] + ko, d + 8192);
        load_lds_16(bpS[0] + ko, d + 16384);
        load_lds_16(bpS[1] + ko, d + 24576);
    };

    const int slotS = (((lane & 1) << 2) + quad) ^ ((lc >> 1) & 7);
    const int aoff = (wm * 64 + (lc >> 1)) * 128 + slotS * 16;
    const int boff = 16384 + (wn * 32 + (lc >> 1)) * 128 + slotS * 16;

    short8 af[8], bf[4];
    auto readfr = [&](int buf) {
        const uint8_t* p = smem + buf * 32768;
#pragma unroll
        for (int m = 0; m < 8; ++m) af[m] = *(const short8*)(p + aoff + m * 1024);
#pragma unroll
        for (int n = 0; n < 4; ++n) bf[n] = *(const short8*)(p + boff + n * 1024);
    };

    f32x4 acc[8][4] = {};
    auto mfmas = [&]() {
        __builtin_amdgcn_s_setprio(1);
#pragma unroll
        for (int m = 0; m < 8; ++m)
#pragma unroll
            for (int n = 0; n < 4; ++n)
                acc[m][n] = __builtin_amdgcn_mfma_f32_16x16x32_bf16(af[m], bf[n], acc[m][n], 0, 0, 0);
        __builtin_amdgcn_s_setprio(0);
    };

    stage(0, 0);
    stage(1, 1);
    asm volatile("s_waitcnt vmcnt(4)" ::: "memory");
    __builtin_amdgcn_s_barrier();

#pragma unroll 1
    for (int t3 = 0; t3 < 7; ++t3) {
        const int T = t3 * 3;
#pragma unroll
        for (int u = 0; u < 3; ++u) {
            const int sb = (u + 2) % 3;
            stage(T + u + 2, sb);
            readfr(u);
            mfmas();
            asm volatile("s_waitcnt vmcnt(4)" ::: "memory");
            __builtin_amdgcn_s_barrier();
        }
    }
    stage(23, 2);
    readfr(0);
    mfmas();
    asm volatile("s_waitcnt vmcnt(4)" ::: "memory");
    __builtin_amdgcn_s_barrier();
    readfr(1);
    mfmas();
    asm volatile("s_waitcnt vmcnt(0)" ::: "memory");
    __builtin_amdgcn_s_barrier();
    readfr(2);
    mfmas();
    __builtin_amdgcn_s_barrier();

    float bv[4];
#pragma unroll
    for (int j = 0; j < 4; ++j) bv[j] = bias[tn + wn * 64 + j * 16 + lc];

    float* ep = (float*)smem + wave * (16 * 68);
    const int erow = lane >> 2, ec = (lane & 3) * 16;
#pragma unroll
    for (int ia = 0; ia < 8; ++ia) {
#pragma unroll
        for (int j = 0; j < 4; ++j)
#pragma unroll
            for (int r = 0; r < 4; ++r)
                ep[(quad * 4 + r) * 68 + j * 16 + lc] = acc[ia][j][r] + bv[j];
        __threadfence_block();
        int grow = tm + wm * 128 + ia * 16 + erow;
        if (grow < Mm) {
            float4 c0 = *(float4*)&ep[erow * 68 + ec + 0];
            float4 c1 = *(float4*)&ep[erow * 68 + ec + 4];
            float4 c2 = *(float4*)&ep[erow * 68 + ec + 8];
            float4 c3 = *(float4*)&ep[erow * 68 + ec + 12];
            int gcol = tn + wn * 64 + ec;
            if constexpr (OUT_BF16) {
                unsigned short o[16];
                *(ushort2*)&o[0]  = f2b2(c0.x, c0.y);
                *(ushort2*)&o[2]  = f2b2(c0.z, c0.w);
                *(ushort2*)&o[4]  = f2b2(c1.x, c1.y);
                *(ushort2*)&o[6]  = f2b2(c1.z, c1.w);
                *(ushort2*)&o[8]  = f2b2(c2.x, c2.y);
                *(ushort2*)&o[10] = f2b2(c2.z, c2.w);
                *(ushort2*)&o[12] = f2b2(c3.x, c3.y);
                *(ushort2*)&o[14] = f2b2(c3.z, c3.w);
                unsigned short* op = (unsigned short*)Cout + (size_t)grow * N_ + gcol;
                *(short8*)(op + 0) = *(short8*)&o[0];
                *(short8*)(op + 8) = *(short8*)&o[8];
            } else {
                float* op = (float*)Cout + (size_t)grow * N_ + gcol;
                *(float4*)(op + 0)  = c0;
                *(float4*)(op + 4)  = c1;
                *(float4*)(op + 8)  = c2;
                *(float4*)(op + 12) = c3;
            }
        }
        __threadfence_block();
    }
}

// ---------------- flash attention: 4 waves x 64q; all-LDS chunk-XOR swizzled ----------------
// attn was DS-pipe bound (r7: 91us, VALUBusy 43%, 6.4M conflicts, ~400 LDS-cyc
// per wave-tile for 32q). This version: 64 q/wave (K/V frags reused 4 q-halves),
// stride-64 chunk-XOR layouts everywhere (the gemm's measured-0-conflict scheme),
// l-sum via constant all-ones A-operand (no ones-row LDS, no shfl for l).
// Layouts (shorts): X[row][64], elem (row, c) at row*64 + ((c>>3)^(row&7))*8 + (c&7).
//   Kt: row=key, c=dh.  Vt: row=dh,  c=key.  Pq (per wave): row=q', c=key; reused for O (c=dh).
__global__ __launch_bounds__(256, 2)
void attn_kernel(const unsigned short* __restrict__ qkv,   // [Mm][2304] bf16
                 unsigned short* __restrict__ outb) {      // [Mm][768] bf16
    __shared__ unsigned short Kt[2][64 * 64];   // 16 KB
    __shared__ unsigned short Vt[2][64 * 64];   // 16 KB (V^T)
    __shared__ unsigned short Pq[4][64 * 64];   // 32 KB per-wave P / O staging

    const int tid = threadIdx.x;
    const int wave = tid >> 6, lane = tid & 63;
    const int quad = lane >> 4, lc = lane & 15;
    const int lsw = lc & 7;

    const int orig = (blockIdx.z * gridDim.y + blockIdx.y) * gridDim.x + blockIdx.x;
    const int wgid = (orig & 7) * 144 + (orig >> 3);   // 1152 blocks, 144/XCD
    const int qt = wgid % 3;
    const int h  = (wgid / 3) % Hh;
    const int b  = wgid / (3 * Hh);

    const unsigned short* qkvK = qkv + (size_t)b * Ss * QKV_N + h * 64 + 768;
    const unsigned short* qkvV = qkvK + 768;

    const int krow = lane >> 3;
    const int gch = (lane & 7) ^ krow;

    const int qbase = qt * 256 + wave * 64;
    short8 qf[4][2];
#pragma unroll
    for (int hf = 0; hf < 4; ++hf) {
        int qrow = qbase + hf * 16 + lc; if (qrow > Ss - 1) qrow = Ss - 1;
        const unsigned short* qp = qkv + (size_t)(b * Ss + qrow) * QKV_N + h * 64;
        qf[hf][0] = *(const short8*)(qp + quad * 8);
        qf[hf][1] = *(const short8*)(qp + 32 + quad * 8);
    }

    unsigned short* Pqw = Pq[wave];

    short8 ones;
#pragma unroll
    for (int j = 0; j < 8; ++j) ones[j] = (short)0x3F80;   // bf16 1.0

    auto stage_K = [&](int tile, int buf) {
#pragma unroll
        for (int s = 0; s < 2; ++s) {
            int key = tile * 64 + s * 32 + wave * 8 + krow;   // tile<=8 -> key<=575
            load_lds_16(qkvK + (size_t)key * QKV_N + gch * 8,
                        (void*)&Kt[buf][(s * 32 + wave * 8) * 64]);
        }
    };
    auto load_V = [&](int tile, short8 v[2]) {
        int key = tile * 64 + lane;
#pragma unroll
        for (int s = 0; s < 2; ++s)
            v[s] = *(const short8*)(qkvV + (size_t)key * QKV_N + (s * 32 + wave * 8));
    };
    auto write_V = [&](short8 v[2], int buf) {
#pragma unroll
        for (int s = 0; s < 2; ++s)
#pragma unroll
            for (int j = 0; j < 8; ++j) {
                int d = s * 32 + wave * 8 + j;
                Vt[buf][d * 64 + ((((lane >> 3) ^ (d & 7)) << 3) | (lane & 7))] =
                    (unsigned short)v[s][j];
            }
    };

    f32x4 oacc[4][4] = {};
    f32x4 lacc[4] = {};

    auto tile_compute = [&](int buf) {
        // K frags once per tile, reused by all 4 q-halves
        short8 k0[4], k1[4];
#pragma unroll
        for (int f = 0; f < 4; ++f) {
            const unsigned short* kr = &Kt[buf][(f * 16 + lc) * 64];
            k0[f] = *(const short8*)(kr + ((quad ^ lsw) << 3));
            k1[f] = *(const short8*)(kr + (((quad ^ 4) ^ lsw) << 3));
        }
#pragma unroll
        for (int hf = 0; hf < 4; ++hf) {
            f32x4 sfr[4];
            __builtin_amdgcn_s_setprio(1);
#pragma unroll
            for (int f = 0; f < 4; ++f) {
                f32x4 z = {};
                z = __builtin_amdgcn_mfma_f32_16x16x32_bf16(k0[f], qf[hf][0], z, 0, 0, 0);
                z = __builtin_amdgcn_mfma_f32_16x16x32_bf16(k1[f], qf[hf][1], z, 0, 0, 0);
                sfr[f] = z;
            }
            __builtin_amdgcn_s_setprio(0);
            const int qrow64 = (hf * 16 + lc) * 64;
#pragma unroll
            for (int f = 0; f < 4; ++f) {
                float p0 = __builtin_amdgcn_exp2f(sfr[f][0] * SCALE_L2E);
                float p1 = __builtin_amdgcn_exp2f(sfr[f][1] * SCALE_L2E);
                float p2 = __builtin_amdgcn_exp2f(sfr[f][2] * SCALE_L2E);
                float p3 = __builtin_amdgcn_exp2f(sfr[f][3] * SCALE_L2E);
                ushort2 lo = f2b2(p0, p1), hi = f2b2(p2, p3);
                ushort4 pk = {lo.x, lo.y, hi.x, hi.y};
                *(ushort4*)&Pqw[qrow64 + ((((2 * f + (quad >> 1)) ^ lsw) << 3) | ((quad & 1) << 2))] = pk;
            }
        }
        __threadfence_block();   // wave-local P visibility (per-wave buffer)

        short8 pf[4][2];
#pragma unroll
        for (int hf = 0; hf < 4; ++hf) {
            const int qrow64 = (hf * 16 + lc) * 64;
            pf[hf][0] = *(const short8*)&Pqw[qrow64 + ((quad ^ lsw) << 3)];
            pf[hf][1] = *(const short8*)&Pqw[qrow64 + (((quad ^ 4) ^ lsw) << 3)];
        }
        __builtin_amdgcn_s_setprio(1);
#pragma unroll
        for (int g = 0; g < 4; ++g) {
            const unsigned short* vr = &Vt[buf][(g * 16 + lc) * 64];
            short8 vf0 = *(const short8*)(vr + ((quad ^ lsw) << 3));
            short8 vf1 = *(const short8*)(vr + (((quad ^ 4) ^ lsw) << 3));
#pragma unroll
            for (int hf = 0; hf < 4; ++hf) {
                oacc[hf][g] = __builtin_amdgcn_mfma_f32_16x16x32_bf16(vf0, pf[hf][0], oacc[hf][g], 0, 0, 0);
                oacc[hf][g] = __builtin_amdgcn_mfma_f32_16x16x32_bf16(vf1, pf[hf][1], oacc[hf][g], 0, 0, 0);
            }
        }
#pragma unroll
        for (int hf = 0; hf < 4; ++hf) {
            lacc[hf] = __builtin_amdgcn_mfma_f32_16x16x32_bf16(ones, pf[hf][0], lacc[hf], 0, 0, 0);
            lacc[hf] = __builtin_amdgcn_mfma_f32_16x16x32_bf16(ones, pf[hf][1], lacc[hf], 0, 0, 0);
        }
        __builtin_amdgcn_s_setprio(0);
    };

    short8 vreg[2];
    stage_K(0, 0);
    load_V(0, vreg);
    write_V(vreg, 0);
    __syncthreads();

    for (int kb = 0; kb < 8; ++kb) {
        const int buf = kb & 1;
        stage_K(kb + 1, buf ^ 1);
        load_V(kb + 1, vreg);
        tile_compute(buf);
        write_V(vreg, buf ^ 1);
        __syncthreads();
    }
    tile_compute(0);   // tile 8 (buf 0)

    // ---- key 576 tail per q-half (register VALU)
    float ptl[4];
    {
        const unsigned short* k576 = qkvK + (size_t)576 * QKV_N;
        short8 kk0 = *(const short8*)(k576 + quad * 8);
        short8 kk1 = *(const short8*)(k576 + 32 + quad * 8);
        const unsigned short* v576 = qkvV + (size_t)576 * QKV_N;
#pragma unroll
        for (int hf = 0; hf < 4; ++hf) {
            float part = 0.f;
#pragma unroll
            for (int j = 0; j < 8; ++j)
                part += b2f((unsigned short)qf[hf][0][j]) * b2f((unsigned short)kk0[j])
                      + b2f((unsigned short)qf[hf][1][j]) * b2f((unsigned short)kk1[j]);
            part += __shfl_xor(part, 16, 64);
            part += __shfl_xor(part, 32, 64);
            ptl[hf] = __builtin_amdgcn_exp2f(part * SCALE_L2E);
#pragma unroll
            for (int g = 0; g < 4; ++g) {
                ushort4 vv = *(const ushort4*)(v576 + g * 16 + quad * 4);
                oacc[hf][g][0] += ptl[hf] * b2f(vv.x);
                oacc[hf][g][1] += ptl[hf] * b2f(vv.y);
                oacc[hf][g][2] += ptl[hf] * b2f(vv.z);
                oacc[hf][g][3] += ptl[hf] * b2f(vv.w);
            }
        }
    }

    // ---- epilogue: l = lacc[hf][0] (every lane holds l[q=lc]); O -> swizzled Pq -> store
#pragma unroll
    for (int hf = 0; hf < 4; ++hf) {
        float inv = 1.f / (lacc[hf][0] + ptl[hf]);
        const int qrow64 = (hf * 16 + lc) * 64;
#pragma unroll
        for (int g = 0; g < 4; ++g) {
            ushort2 lo = f2b2(oacc[hf][g][0] * inv, oacc[hf][g][1] * inv);
            ushort2 hi = f2b2(oacc[hf][g][2] * inv, oacc[hf][g][3] * inv);
            ushort4 ob = {lo.x, lo.y, hi.x, hi.y};
            *(ushort4*)&Pqw[qrow64 + ((((2 * g + (quad >> 1)) ^ lsw) << 3) | ((quad & 1) << 2))] = ob;
        }
    }
    __threadfence_block();
#pragma unroll
    for (int p = 0; p < 8; ++p) {
        int lr = p * 8 + (lane >> 3), ch = lane & 7;
        int q = qbase + lr;
        if (q <= Ss - 1) {
            short8 vv = *(const short8*)&Pqw[lr * 64 + ((ch ^ (lr & 7)) << 3)];
            *(short8*)(outb + (size_t)(b * Ss + q) * Dd + h * 64 + ch * 8) = vv;
        }
    }
}

extern "C" void kernel_launch(void* const* d_in, const int* in_sizes, int n_in,
                              void* d_out, int out_size, void* d_ws, size_t ws_size,
                              hipStream_t stream) {
    const float* x     = (const float*)d_in[0];
    const float* w_qkv = (const float*)d_in[1];
    const float* b_qkv = (const float*)d_in[2];
    const float* w_fc  = (const float*)d_in[3];
    const float* b_fc  = (const float*)d_in[4];

    uint8_t* ws = (uint8_t*)d_ws;
    unsigned short* xb    = (unsigned short*)(ws + 0);           //  28,360,704 B
    unsigned short* wqkvT = (unsigned short*)(ws + 28360704);    //   3,538,944 B
    unsigned short* wfcT  = (unsigned short*)(ws + 31899648);    //   1,179,648 B
    unsigned short* qkv   = (unsigned short*)(ws + 33079296);    //  85,082,112 B
    unsigned short* attn  = (unsigned short*)(ws + 118161408);   //  28,360,704 B

    static bool lds_init = false;
    if (!lds_init) {
        hipFuncSetAttribute((const void*)gemm256<QKV_N, true>,
                            hipFuncAttributeMaxDynamicSharedMemorySize, 98304);
        hipFuncSetAttribute((const void*)gemm256<Dd, false>,
                            hipFuncAttributeMaxDynamicSharedMemorySize, 98304);
        lds_init = true;
    }

    constexpr int PREP_GRID = (Mm * Dd / 4) / 256 + (QKV_N / 32) * (Dd / 32) + (Dd / 32) * (Dd / 32);
    prep_fused<<<PREP_GRID, 256, 0, stream>>>(x, xb, w_qkv, wqkvT, w_fc, wfcT);

    gemm256<QKV_N, true><<<dim3(QKV_N / 256, (Mm + 255) / 256), 512, 98304, stream>>>(xb, wqkvT, b_qkv, qkv);

    attn_kernel<<<dim3(3, Hh, Bz), 256, 0, stream>>>(qkv, attn);

    gemm256<Dd, false><<<dim3(Dd / 256, (Mm + 255) / 256), 512, 98304, stream>>>(attn, wfcT, b_fc, d_out);
}

// Round 9
// 295.800 us; speedup vs baseline: 1.0779x; 1.0779x over previous
//
#include <hip/hip_runtime.h>
#include <hip/hip_bf16.h>
#include <stdint.h>

typedef __attribute__((ext_vector_type(8))) short short8;   // 8 bf16 = 4 VGPRs
typedef __attribute__((ext_vector_type(4))) float f32x4;    // MFMA C/D frag

typedef __attribute__((address_space(3))) uint8_t lds_u8;
typedef __attribute__((address_space(1))) uint8_t glb_u8;

__device__ __forceinline__ void load_lds_16(const void* g, void* l) {
    __builtin_amdgcn_global_load_lds((glb_u8*)g, (lds_u8*)l, 16, 0, 0);
}

__device__ __forceinline__ unsigned short f2b(float f) {
    __hip_bfloat16 h = __float2bfloat16(f);
    return __builtin_bit_cast(unsigned short, h);
}
__device__ __forceinline__ ushort2 f2b2(float a, float b) {
    __hip_bfloat162 h = __float22bfloat162_rn(float2{a, b});
    ushort2 r;
    __builtin_memcpy(&r, &h, sizeof(r));
    return r;
}
__device__ __forceinline__ float b2f(unsigned short u) {
    unsigned int x = ((unsigned int)u) << 16;
    return __builtin_bit_cast(float, x);
}

constexpr int Bz = 32, Ss = 577, Dd = 768, Hh = 12;
constexpr int Mm = Bz * Ss;          // 18464
constexpr int QKV_N = 3 * Dd;        // 2304
constexpr float SCALE_L2E = 0.125f * 1.4426950408889634f;

// ---------------- fused prep: cast x->bf16 + both weight transposes ----------------
__global__ void prep_fused(const float* __restrict__ x, unsigned short* __restrict__ xb,
                           const float* __restrict__ w_qkv, unsigned short* __restrict__ wqkvT,
                           const float* __restrict__ w_fc, unsigned short* __restrict__ wfcT) {
    constexpr int N4 = Mm * Dd / 4;
    constexpr int NC = N4 / 256;
    constexpr int NT1 = (QKV_N / 32) * (Dd / 32);
    __shared__ unsigned short tile[32][33];

    const int bid = blockIdx.x;
    const int tid = threadIdx.x;
    if (bid < NC) {
        int i = bid * 256 + tid;
        float4 v = ((const float4*)x)[i];
        ushort4 o;
        o.x = f2b(v.x); o.y = f2b(v.y); o.z = f2b(v.z); o.w = f2b(v.w);
        ((ushort4*)xb)[i] = o;
        return;
    }
    const float* src; unsigned short* dst; int R, C, bx, by;
    if (bid < NC + NT1) {
        int b2 = bid - NC;
        src = w_qkv; dst = wqkvT; R = Dd; C = QKV_N;
        bx = b2 % (QKV_N / 32); by = b2 / (QKV_N / 32);
    } else {
        int b2 = bid - NC - NT1;
        src = w_fc; dst = wfcT; R = Dd; C = Dd;
        bx = b2 % (Dd / 32); by = b2 / (Dd / 32);
    }
    int c0 = bx * 32, r0 = by * 32;
    int tx = tid & 31, ty = tid >> 5;
#pragma unroll
    for (int i = 0; i < 4; ++i)
        tile[ty + i * 8][tx] = f2b(src[(size_t)(r0 + ty + i * 8) * C + c0 + tx]);
    __syncthreads();
#pragma unroll
    for (int i = 0; i < 4; ++i) {
        int rr = ty + i * 8;
        dst[(size_t)(c0 + rr) * R + r0 + tx] = tile[tx][rr];
    }
}

// ========= 256x256 TN GEMM, BK=32, triple-buffered counted-vmcnt (r6, 82us) =========
// Structural operating point under 1-block/CU lockstep (acc = 128 regs; r3 lesson).
template <int N_, bool OUT_BF16>
__global__ __launch_bounds__(512, 2)
void gemm256(const unsigned short* __restrict__ A,
             const unsigned short* __restrict__ Bt,
             const float* __restrict__ bias,
             void* __restrict__ Cout) {
    constexpr int K = 768;
    constexpr int NX = N_ / 256;
    constexpr int NY = (Mm + 255) / 256; // 73
    constexpr int NWG = NX * NY;
    constexpr int QC = NWG >> 3, RC = NWG & 7;
    extern __shared__ __align__(16) uint8_t smem[];   // 98304 B

    const int tid = threadIdx.x;
    const int wave = tid >> 6, lane = tid & 63;
    const int quad = lane >> 4, lc = lane & 15;
    const int wm = wave >> 2, wn = wave & 3;

    const int orig = blockIdx.y * NX + blockIdx.x;
    const int xcd = orig & 7, lid = orig >> 3;
    const int wgid = (xcd < RC ? xcd * (QC + 1) : RC * (QC + 1) + (xcd - RC) * QC) + lid;
    const int tm = (wgid / NX) * 256;
    const int tn = (wgid % NX) * 256;

    const int lrw = wave * 8 + (lane >> 3);
    const unsigned short* apS[2];
    const unsigned short* bpS[2];
#pragma unroll
    for (int s = 0; s < 2; ++s) {
        const int lr = s * 64 + lrw;
        const int chun = (lane & 7) ^ (lr & 7);
        const int trow = lr * 2 + (chun >> 2);
        int ar = tm + trow; if (ar >= Mm) ar = Mm - 1;
        apS[s] = A + (size_t)ar * K + (chun & 3) * 8;
        const int br = tn + trow;
        bpS[s] = Bt + (size_t)br * K + (chun & 3) * 8;
    }

    auto stage = [&](int kb, int buf) {
        uint8_t* d = smem + buf * 32768 + wave * 1024;
        const int ko = kb * 32;
        load_lds_16(apS[0] + ko, d);
        load_lds_16(apS[1] + ko, d + 8192);
        load_lds_16(bpS[0] + ko, d + 16384);
        load_lds_16(bpS[1] + ko, d + 24576);
    };

    const int slotS = (((lane & 1) << 2) + quad) ^ ((lc >> 1) & 7);
    const int aoff = (wm * 64 + (lc >> 1)) * 128 + slotS * 16;
    const int boff = 16384 + (wn * 32 + (lc >> 1)) * 128 + slotS * 16;

    short8 af[8], bf[4];
    auto readfr = [&](int buf) {
        const uint8_t* p = smem + buf * 32768;
#pragma unroll
        for (int m = 0; m < 8; ++m) af[m] = *(const short8*)(p + aoff + m * 1024);
#pragma unroll
        for (int n = 0; n < 4; ++n) bf[n] = *(const short8*)(p + boff + n * 1024);
    };

    f32x4 acc[8][4] = {};
    auto mfmas = [&]() {
        __builtin_amdgcn_s_setprio(1);
#pragma unroll
        for (int m = 0; m < 8; ++m)
#pragma unroll
            for (int n = 0; n < 4; ++n)
                acc[m][n] = __builtin_amdgcn_mfma_f32_16x16x32_bf16(af[m], bf[n], acc[m][n], 0, 0, 0);
        __builtin_amdgcn_s_setprio(0);
    };

    stage(0, 0);
    stage(1, 1);
    asm volatile("s_waitcnt vmcnt(4)" ::: "memory");
    __builtin_amdgcn_s_barrier();

#pragma unroll 1
    for (int t3 = 0; t3 < 7; ++t3) {
        const int T = t3 * 3;
#pragma unroll
        for (int u = 0; u < 3; ++u) {
            const int sb = (u + 2) % 3;
            stage(T + u + 2, sb);
            readfr(u);
            mfmas();
            asm volatile("s_waitcnt vmcnt(4)" ::: "memory");
            __builtin_amdgcn_s_barrier();
        }
    }
    stage(23, 2);
    readfr(0);
    mfmas();
    asm volatile("s_waitcnt vmcnt(4)" ::: "memory");
    __builtin_amdgcn_s_barrier();
    readfr(1);
    mfmas();
    asm volatile("s_waitcnt vmcnt(0)" ::: "memory");
    __builtin_amdgcn_s_barrier();
    readfr(2);
    mfmas();
    __builtin_amdgcn_s_barrier();

    float bv[4];
#pragma unroll
    for (int j = 0; j < 4; ++j) bv[j] = bias[tn + wn * 64 + j * 16 + lc];

    float* ep = (float*)smem + wave * (16 * 68);
    const int erow = lane >> 2, ec = (lane & 3) * 16;
#pragma unroll
    for (int ia = 0; ia < 8; ++ia) {
#pragma unroll
        for (int j = 0; j < 4; ++j)
#pragma unroll
            for (int r = 0; r < 4; ++r)
                ep[(quad * 4 + r) * 68 + j * 16 + lc] = acc[ia][j][r] + bv[j];
        __threadfence_block();
        int grow = tm + wm * 128 + ia * 16 + erow;
        if (grow < Mm) {
            float4 c0 = *(float4*)&ep[erow * 68 + ec + 0];
            float4 c1 = *(float4*)&ep[erow * 68 + ec + 4];
            float4 c2 = *(float4*)&ep[erow * 68 + ec + 8];
            float4 c3 = *(float4*)&ep[erow * 68 + ec + 12];
            int gcol = tn + wn * 64 + ec;
            if constexpr (OUT_BF16) {
                unsigned short o[16];
                *(ushort2*)&o[0]  = f2b2(c0.x, c0.y);
                *(ushort2*)&o[2]  = f2b2(c0.z, c0.w);
                *(ushort2*)&o[4]  = f2b2(c1.x, c1.y);
                *(ushort2*)&o[6]  = f2b2(c1.z, c1.w);
                *(ushort2*)&o[8]  = f2b2(c2.x, c2.y);
                *(ushort2*)&o[10] = f2b2(c2.z, c2.w);
                *(ushort2*)&o[12] = f2b2(c3.x, c3.y);
                *(ushort2*)&o[14] = f2b2(c3.z, c3.w);
                unsigned short* op = (unsigned short*)Cout + (size_t)grow * N_ + gcol;
                *(short8*)(op + 0) = *(short8*)&o[0];
                *(short8*)(op + 8) = *(short8*)&o[8];
            } else {
                float* op = (float*)Cout + (size_t)grow * N_ + gcol;
                *(float4*)(op + 0)  = c0;
                *(float4*)(op + 4)  = c1;
                *(float4*)(op + 8)  = c2;
                *(float4*)(op + 12) = c3;
            }
        }
        __threadfence_block();
    }
}

// ------------- flash attention: 4 waves x 32q, 48KB LDS -> 3 blocks/CU -------------
// r7 geometry (grid 1920, 1.11x q-padding) + r8's verified layouts: all LDS
// stride-64 chunk-XOR (conflict-halver), l-sum via constant all-ones A-operand
// (no ones-row, no l-shfl). LDS 48KB (was 57.8/64) -> 3 blocks/CU = 12 waves/CU
// for the latency-bound QK->exp2->P->PV chain (r8 diagnosis: 18% Mfma / 33%
// VALU / 8.5% HBM at 6 waves/CU = dependency-latency bound).
// Layouts (shorts): X[row][64], elem (row,c) at row*64 + ((c>>3)^(row&7))*8 + (c&7).
__global__ __launch_bounds__(256, 3)
void attn_kernel(const unsigned short* __restrict__ qkv,   // [Mm][2304] bf16
                 unsigned short* __restrict__ outb) {      // [Mm][768] bf16
    __shared__ unsigned short Kt[2][64 * 64];   // 16 KB
    __shared__ unsigned short Vt[2][64 * 64];   // 16 KB (V^T)
    __shared__ unsigned short Pq[4][32 * 64];   // 16 KB per-wave P / O staging

    const int tid = threadIdx.x;
    const int wave = tid >> 6, lane = tid & 63;
    const int quad = lane >> 4, lc = lane & 15;
    const int lsw = lc & 7;

    const int orig = (blockIdx.z * gridDim.y + blockIdx.y) * gridDim.x + blockIdx.x;
    const int wgid = (orig & 7) * 240 + (orig >> 3);   // 1920 blocks, 240/XCD
    const int qt = wgid % 5;
    const int h  = (wgid / 5) % Hh;
    const int b  = wgid / (5 * Hh);

    const unsigned short* qkvK = qkv + (size_t)b * Ss * QKV_N + h * 64 + 768;
    const unsigned short* qkvV = qkvK + 768;

    const int krow = lane >> 3;
    const int gch = (lane & 7) ^ krow;

    const int qbase = qt * 128 + wave * 32;
    short8 qf[2][2];
#pragma unroll
    for (int hf = 0; hf < 2; ++hf) {
        int qrow = qbase + hf * 16 + lc; if (qrow > Ss - 1) qrow = Ss - 1;
        const unsigned short* qp = qkv + (size_t)(b * Ss + qrow) * QKV_N + h * 64;
        qf[hf][0] = *(const short8*)(qp + quad * 8);
        qf[hf][1] = *(const short8*)(qp + 32 + quad * 8);
    }

    unsigned short* Pqw = Pq[wave];

    short8 ones;
#pragma unroll
    for (int j = 0; j < 8; ++j) ones[j] = (short)0x3F80;   // bf16 1.0

    auto stage_K = [&](int tile, int buf) {
#pragma unroll
        for (int s = 0; s < 2; ++s) {
            int key = tile * 64 + s * 32 + wave * 8 + krow;   // tile<=8 -> key<=575
            load_lds_16(qkvK + (size_t)key * QKV_N + gch * 8,
                        (void*)&Kt[buf][(s * 32 + wave * 8) * 64]);
        }
    };
    auto load_V = [&](int tile, short8 v[2]) {
        int key = tile * 64 + lane;
#pragma unroll
        for (int s = 0; s < 2; ++s)
            v[s] = *(const short8*)(qkvV + (size_t)key * QKV_N + (s * 32 + wave * 8));
    };
    auto write_V = [&](short8 v[2], int buf) {
#pragma unroll
        for (int s = 0; s < 2; ++s)
#pragma unroll
            for (int j = 0; j < 8; ++j) {
                int d = s * 32 + wave * 8 + j;
                Vt[buf][d * 64 + ((((lane >> 3) ^ (d & 7)) << 3) | (lane & 7))] =
                    (unsigned short)v[s][j];
            }
    };

    f32x4 oacc[2][4] = {};
    f32x4 lacc[2] = {};

    auto tile_compute = [&](int buf) {
        // K frags once per tile, reused by both q-halves
        short8 k0[4], k1[4];
#pragma unroll
        for (int f = 0; f < 4; ++f) {
            const unsigned short* kr = &Kt[buf][(f * 16 + lc) * 64];
            k0[f] = *(const short8*)(kr + ((quad ^ lsw) << 3));
            k1[f] = *(const short8*)(kr + (((quad ^ 4) ^ lsw) << 3));
        }
#pragma unroll
        for (int hf = 0; hf < 2; ++hf) {
            f32x4 sfr[4];
            __builtin_amdgcn_s_setprio(1);
#pragma unroll
            for (int f = 0; f < 4; ++f) {
                f32x4 z = {};
                z = __builtin_amdgcn_mfma_f32_16x16x32_bf16(k0[f], qf[hf][0], z, 0, 0, 0);
                z = __builtin_amdgcn_mfma_f32_16x16x32_bf16(k1[f], qf[hf][1], z, 0, 0, 0);
                sfr[f] = z;
            }
            __builtin_amdgcn_s_setprio(0);
            const int qrow64 = (hf * 16 + lc) * 64;
#pragma unroll
            for (int f = 0; f < 4; ++f) {
                float p0 = __builtin_amdgcn_exp2f(sfr[f][0] * SCALE_L2E);
                float p1 = __builtin_amdgcn_exp2f(sfr[f][1] * SCALE_L2E);
                float p2 = __builtin_amdgcn_exp2f(sfr[f][2] * SCALE_L2E);
                float p3 = __builtin_amdgcn_exp2f(sfr[f][3] * SCALE_L2E);
                ushort2 lo = f2b2(p0, p1), hi = f2b2(p2, p3);
                ushort4 pk = {lo.x, lo.y, hi.x, hi.y};
                *(ushort4*)&Pqw[qrow64 + ((((2 * f + (quad >> 1)) ^ lsw) << 3) | ((quad & 1) << 2))] = pk;
            }
        }
        __threadfence_block();   // wave-local P visibility (per-wave buffer)

        short8 pf[2][2];
#pragma unroll
        for (int hf = 0; hf < 2; ++hf) {
            const int qrow64 = (hf * 16 + lc) * 64;
            pf[hf][0] = *(const short8*)&Pqw[qrow64 + ((quad ^ lsw) << 3)];
            pf[hf][1] = *(const short8*)&Pqw[qrow64 + (((quad ^ 4) ^ lsw) << 3)];
        }
        __builtin_amdgcn_s_setprio(1);
#pragma unroll
        for (int g = 0; g < 4; ++g) {
            const unsigned short* vr = &Vt[buf][(g * 16 + lc) * 64];
            short8 vf0 = *(const short8*)(vr + ((quad ^ lsw) << 3));
            short8 vf1 = *(const short8*)(vr + (((quad ^ 4) ^ lsw) << 3));
#pragma unroll
            for (int hf = 0; hf < 2; ++hf) {
                oacc[hf][g] = __builtin_amdgcn_mfma_f32_16x16x32_bf16(vf0, pf[hf][0], oacc[hf][g], 0, 0, 0);
                oacc[hf][g] = __builtin_amdgcn_mfma_f32_16x16x32_bf16(vf1, pf[hf][1], oacc[hf][g], 0, 0, 0);
            }
        }
#pragma unroll
        for (int hf = 0; hf < 2; ++hf) {
            lacc[hf] = __builtin_amdgcn_mfma_f32_16x16x32_bf16(ones, pf[hf][0], lacc[hf], 0, 0, 0);
            lacc[hf] = __builtin_amdgcn_mfma_f32_16x16x32_bf16(ones, pf[hf][1], lacc[hf], 0, 0, 0);
        }
        __builtin_amdgcn_s_setprio(0);
    };

    short8 vreg[2];
    stage_K(0, 0);
    load_V(0, vreg);
    write_V(vreg, 0);
    __syncthreads();

    for (int kb = 0; kb < 8; ++kb) {
        const int buf = kb & 1;
        stage_K(kb + 1, buf ^ 1);
        load_V(kb + 1, vreg);
        tile_compute(buf);
        write_V(vreg, buf ^ 1);
        __syncthreads();
    }
    tile_compute(0);   // tile 8 (buf 0)

    // ---- key 576 tail per q-half (register VALU)
    float ptl[2];
    {
        const unsigned short* k576 = qkvK + (size_t)576 * QKV_N;
        short8 kk0 = *(const short8*)(k576 + quad * 8);
        short8 kk1 = *(const short8*)(k576 + 32 + quad * 8);
        const unsigned short* v576 = qkvV + (size_t)576 * QKV_N;
#pragma unroll
        for (int hf = 0; hf < 2; ++hf) {
            float part = 0.f;
#pragma unroll
            for (int j = 0; j < 8; ++j)
                part += b2f((unsigned short)qf[hf][0][j]) * b2f((unsigned short)kk0[j])
                      + b2f((unsigned short)qf[hf][1][j]) * b2f((unsigned short)kk1[j]);
            part += __shfl_xor(part, 16, 64);
            part += __shfl_xor(part, 32, 64);
            ptl[hf] = __builtin_amdgcn_exp2f(part * SCALE_L2E);
#pragma unroll
            for (int g = 0; g < 4; ++g) {
                ushort4 vv = *(const ushort4*)(v576 + g * 16 + quad * 4);
                oacc[hf][g][0] += ptl[hf] * b2f(vv.x);
                oacc[hf][g][1] += ptl[hf] * b2f(vv.y);
                oacc[hf][g][2] += ptl[hf] * b2f(vv.z);
                oacc[hf][g][3] += ptl[hf] * b2f(vv.w);
            }
        }
    }

    // ---- epilogue: l = lacc[hf][0] (every lane holds l[q=lc]); O -> swizzled Pq -> store
#pragma unroll
    for (int hf = 0; hf < 2; ++hf) {
        float inv = 1.f / (lacc[hf][0] + ptl[hf]);
        const int qrow64 = (hf * 16 + lc) * 64;
#pragma unroll
        for (int g = 0; g < 4; ++g) {
            ushort2 lo = f2b2(oacc[hf][g][0] * inv, oacc[hf][g][1] * inv);
            ushort2 hi = f2b2(oacc[hf][g][2] * inv, oacc[hf][g][3] * inv);
            ushort4 ob = {lo.x, lo.y, hi.x, hi.y};
            *(ushort4*)&Pqw[qrow64 + ((((2 * g + (quad >> 1)) ^ lsw) << 3) | ((quad & 1) << 2))] = ob;
        }
    }
    __threadfence_block();
#pragma unroll
    for (int p = 0; p < 4; ++p) {
        int lr = p * 8 + (lane >> 3), ch = lane & 7;
        int q = qbase + lr;
        if (q <= Ss - 1) {
            short8 vv = *(const short8*)&Pqw[lr * 64 + ((ch ^ (lr & 7)) << 3)];
            *(short8*)(outb + (size_t)(b * Ss + q) * Dd + h * 64 + ch * 8) = vv;
        }
    }
}

extern "C" void kernel_launch(void* const* d_in, const int* in_sizes, int n_in,
                              void* d_out, int out_size, void* d_ws, size_t ws_size,
                              hipStream_t stream) {
    const float* x     = (const float*)d_in[0];
    const float* w_qkv = (const float*)d_in[1];
    const float* b_qkv = (const float*)d_in[2];
    const float* w_fc  = (const float*)d_in[3];
    const float* b_fc  = (const float*)d_in[4];

    uint8_t* ws = (uint8_t*)d_ws;
    unsigned short* xb    = (unsigned short*)(ws + 0);           //  28,360,704 B
    unsigned short* wqkvT = (unsigned short*)(ws + 28360704);    //   3,538,944 B
    unsigned short* wfcT  = (unsigned short*)(ws + 31899648);    //   1,179,648 B
    unsigned short* qkv   = (unsigned short*)(ws + 33079296);    //  85,082,112 B
    unsigned short* attn  = (unsigned short*)(ws + 118161408);   //  28,360,704 B

    static bool lds_init = false;
    if (!lds_init) {
        hipFuncSetAttribute((const void*)gemm256<QKV_N, true>,
                            hipFuncAttributeMaxDynamicSharedMemorySize, 98304);
        hipFuncSetAttribute((const void*)gemm256<Dd, false>,
                            hipFuncAttributeMaxDynamicSharedMemorySize, 98304);
        lds_init = true;
    }

    constexpr int PREP_GRID = (Mm * Dd / 4) / 256 + (QKV_N / 32) * (Dd / 32) + (Dd / 32) * (Dd / 32);
    prep_fused<<<PREP_GRID, 256, 0, stream>>>(x, xb, w_qkv, wqkvT, w_fc, wfcT);

    gemm256<QKV_N, true><<<dim3(QKV_N / 256, (Mm + 255) / 256), 512, 98304, stream>>>(xb, wqkvT, b_qkv, qkv);

    attn_kernel<<<dim3(5, Hh, Bz), 256, 0, stream>>>(qkv, attn);

    gemm256<Dd, false><<<dim3(Dd / 256, (Mm + 255) / 256), 512, 98304, stream>>>(attn, wfcT, b_fc, d_out);
}